// Round 7
// baseline (1499.964 us; speedup 1.0000x reference)
//
#include <hip/hip_runtime.h>
#include <cstddef>

#define NSEQ 20480
#define EPSf 1e-7f
#define MAXN 0.99999f
#define MAXN2 (0.99999f * 0.99999f)

typedef __attribute__((ext_vector_type(8))) short bf16x8;
typedef __attribute__((ext_vector_type(4))) float f32x4;

__device__ __forceinline__ unsigned short f2bf(float x) {
  unsigned u = __float_as_uint(x);
  u += 0x7FFF + ((u >> 16) & 1);
  return (unsigned short)(u >> 16);
}
__device__ __forceinline__ float bf2f(unsigned short h) {
  return __uint_as_float(((unsigned)h) << 16);
}

// ---------------- fold transpose: X[b][l][f] (4 arrays) -> XT[ch][b*64+f][l], ch0 = sum ----------------
__global__ __launch_bounds__(256) void fold_transpose(
    const float* __restrict__ t, const float* __restrict__ c,
    const float* __restrict__ f, const float* __restrict__ r,
    float* __restrict__ XT)
{
  __shared__ float tile[4][56][65];
  const int b = blockIdx.x, l0 = blockIdx.y * 56;
  const int tid = threadIdx.x;
  const int fi = tid & 63, lr0 = tid >> 6;
#pragma unroll
  for (int i = 0; i < 14; ++i) {
    int lr = lr0 + i * 4;
    size_t idx = ((size_t)b * 336 + l0 + lr) * 64 + fi;
    tile[0][lr][fi] = t[idx];
    tile[1][lr][fi] = c[idx];
    tile[2][lr][fi] = f[idx];
    tile[3][lr][fi] = r[idx];
  }
  __syncthreads();
#pragma unroll
  for (int ch = 0; ch < 5; ++ch) {
    for (int i = 0; i < 14; ++i) {
      int idx2 = i * 256 + tid;
      int ff = idx2 / 56, ll = idx2 % 56;
      float v;
      if (ch == 0) v = tile[0][ll][ff] + tile[1][ll][ff] + tile[2][ll][ff] + tile[3][ll][ff];
      else v = tile[ch - 1][ll][ff];
      XT[((size_t)ch * 4096 + (b << 6) + ff) * 336 + l0 + ll] = v;
    }
  }
}

// ---------------- weight split+tile: W[k][n] f32 -> Wh/Wl bf16 at [(k>>3)*N + n]*8 + (k&7) ----------------
__global__ __launch_bounds__(256) void conv_weight(
    const float* __restrict__ W, unsigned short* __restrict__ Wh, unsigned short* __restrict__ Wl,
    int K, int N, int Nsrc)
{
  int idx = blockIdx.x * 256 + threadIdx.x;
  if (idx >= K * N) return;
  int k = idx / N, n = idx % N;
  float x = (n < Nsrc) ? W[(size_t)k * Nsrc + n] : 0.f;
  unsigned short h = f2bf(x);
  size_t o = ((size_t)(k >> 3) * N + n) * 8 + (k & 7);
  Wh[o] = h;
  Wl[o] = f2bf(x - bf2f(h));
}

// ---------------- W_emb -> MFMA B-fragment layout: Wg[T][lane][j], k=8*(lane>>4)+j, n=T*16+(lane&15) ----------------
__global__ __launch_bounds__(256) void conv_wemb(
    const float* __restrict__ W_emb, unsigned short* __restrict__ WgH, unsigned short* __restrict__ WgL)
{
  int idx = blockIdx.x * 256 + threadIdx.x;
  if (idx >= 16 * 64 * 8) return;
  int j = idx & 7, ln = (idx >> 3) & 63, T = idx >> 9;
  int k = 8 * (ln >> 4) + j, n = T * 16 + (ln & 15);
  float x = (k < 24) ? W_emb[(size_t)k * 256 + n] : 0.f;
  unsigned short h = f2bf(x);
  WgH[idx] = h;
  WgL[idx] = f2bf(x - bf2f(h));
}

// ---------------- init: MFMA embed + expmap0 + parallel velocity pairs, one WAVE per sequence ----------------
// C-layout: lane (l4,l15) holds segments s = l4*4+r (r=0..3), cols c = T*16+l15 (T=0..15)
__global__ __launch_bounds__(256) void init_kernel(
    const float* __restrict__ XT,
    const unsigned short* __restrict__ WgH, const unsigned short* __restrict__ WgL,
    const float* __restrict__ b_emb,
    unsigned short* __restrict__ Uh, unsigned short* __restrict__ Ul,
    float* __restrict__ ZL, float* __restrict__ ZN2, unsigned short* __restrict__ VO)
{
  __shared__ unsigned short Bsh[2][16][64][8];   // 32 KB, shared by 4 waves
  __shared__ float segs[4][384];
  __shared__ float bsh[256];
  const int tid = threadIdx.x, w = tid >> 6, lane = tid & 63;
  const int l15 = lane & 15, l4 = lane >> 4;
  const int sidx = blockIdx.x * 4 + w;

  {
    const uint4* srcH = (const uint4*)WgH;       // 8192 shorts = 16384 B = 1024 uint4
    uint4* dstH = (uint4*)&Bsh[0][0][0][0];
    for (int i = tid; i < 1024; i += 256) dstH[i] = srcH[i];
    const uint4* srcL = (const uint4*)WgL;
    uint4* dstL = (uint4*)&Bsh[1][0][0][0];
    for (int i = tid; i < 1024; i += 256) dstL[i] = srcL[i];
    bsh[tid] = b_emb[tid];
  }
  const float* src = XT + (size_t)sidx * 336;
  for (int l = lane; l < 336; l += 64) segs[w][l] = src[l];
  for (int l = 336 + lane; l < 384; l += 64) segs[w][l] = 0.f;
  __syncthreads();

  // A fragment: A[row=l15][k=8*l4+j] = seg[l15*24 + 8*l4 + j]; k>=24 (l4==3) -> 0
  bf16x8 ah, al;
  if (l4 < 3) {
    const float* sp = &segs[w][l15 * 24 + l4 * 8];
    float4 q0 = *(const float4*)sp;
    float4 q1 = *(const float4*)(sp + 4);
    float vv[8] = {q0.x, q0.y, q0.z, q0.w, q1.x, q1.y, q1.z, q1.w};
#pragma unroll
    for (int j = 0; j < 8; ++j) {
      unsigned short h = f2bf(vv[j]);
      ah[j] = (short)h;
      al[j] = (short)f2bf(vv[j] - bf2f(h));
    }
  } else {
#pragma unroll
    for (int j = 0; j < 8; ++j) { ah[j] = 0; al[j] = 0; }
  }

  // 16 N-tiles x 3 split MFMAs
  f32x4 acc[16];
#pragma unroll
  for (int T = 0; T < 16; ++T) acc[T] = (f32x4){0.f, 0.f, 0.f, 0.f};
#pragma unroll
  for (int T = 0; T < 16; ++T) {
    bf16x8 bh = *(const bf16x8*)&Bsh[0][T][lane][0];
    bf16x8 bl = *(const bf16x8*)&Bsh[1][T][lane][0];
    acc[T] = __builtin_amdgcn_mfma_f32_16x16x32_bf16(ah, bh, acc[T], 0, 0, 0);
    acc[T] = __builtin_amdgcn_mfma_f32_16x16x32_bf16(ah, bl, acc[T], 0, 0, 0);
    acc[T] = __builtin_amdgcn_mfma_f32_16x16x32_bf16(al, bh, acc[T], 0, 0, 0);
  }

  // e = tanh(acc + b); norms per segment (f32 butterfly over 16-lane group); expmap0
  float z_[4][16];
  float zn2_[4];
  float ls[4] = {0.f, 0.f, 0.f, 0.f};
#pragma unroll
  for (int T = 0; T < 16; ++T) {
    float b = bsh[T * 16 + l15];
#pragma unroll
    for (int r = 0; r < 4; ++r) {
      float e = tanhf(acc[T][r] + b);
      z_[r][T] = e;
      ls[r] = fmaf(e, e, ls[r]);
    }
  }
#pragma unroll
  for (int m = 1; m < 16; m <<= 1)
#pragma unroll
    for (int r = 0; r < 4; ++r) ls[r] += __shfl_xor(ls[r], m);
#pragma unroll
  for (int r = 0; r < 4; ++r) {
    float vn = sqrtf(fmaxf(ls[r], 1e-14f));
    float tt = tanhf(vn);                 // ||expmap0 pre|| == tanh(||e||) exactly
    bool clip = tt > MAXN;
    float scale = (clip ? MAXN : tt) / vn;
#pragma unroll
    for (int T = 0; T < 16; ++T) z_[r][T] *= scale;
    zn2_[r] = clip ? MAXN2 : tt * tt;
  }

  // cross-group boundary data: next group's reg0 (z and zn2)
  float zsh[16], zn2sh;
#pragma unroll
  for (int T = 0; T < 16; ++T) zsh[T] = __shfl(z_[0][T], (lane + 16) & 63);
  zn2sh = __shfl(zn2_[0], (lane + 16) & 63);

  // velocity pairs: group l4 handles t = 4*l4 + p; groups 0-2: 4 pairs, group 3: 1 pair
  float vel[16];
#pragma unroll
  for (int T = 0; T < 16; ++T) vel[T] = 0.f;
  const float p4c = 0.9f * 0.9f * 0.9f * 0.9f;
  const float p8c = p4c * p4c, p12c = p8c * p4c;
  const float wsum = (1.f - p12c * 0.9f) / 0.1f;
  float wt = ((l4 == 0) ? p12c : (l4 == 1) ? p8c : (l4 == 2) ? p4c : 1.f) / wsum;
  const int npairs = (l4 < 3) ? 4 : 1;
#pragma unroll
  for (int p = 0; p < 4; ++p) {
    if (p < npairs) {
      double sxy = 0.0;
#pragma unroll
      for (int T = 0; T < 16; ++T) {
        float zt1 = (p < 3) ? z_[(p + 1) & 3][T] : zsh[T];
        sxy += (double)z_[p][T] * (double)zt1;
      }
#pragma unroll
      for (int m = 1; m < 16; m <<= 1) sxy += __shfl_xor(sxy, m);   // partners stay in-group
      float x2 = zn2_[p];
      float y2 = (p < 3) ? zn2_[(p + 1) & 3] : zn2sh;
      float xy = (float)sxy;
      float den = fmaxf(1.f - 2.f * xy + x2 * y2, 1e-15f);
      float a2 = (1.f - 2.f * xy + y2) / den;
      float b2c = (1.f - x2) / den;
      float wd[16];
      float sww = 0.f;
#pragma unroll
      for (int T = 0; T < 16; ++T) {
        float zt1 = (p < 3) ? z_[(p + 1) & 3][T] : zsh[T];
        wd[T] = b2c * zt1 - a2 * z_[p][T];
        sww = fmaf(wd[T], wd[T], sww);
      }
#pragma unroll
      for (int m = 1; m < 16; m <<= 1) sww += __shfl_xor(sww, m);
      float wn = sqrtf(fmaxf(sww, 1e-14f));
      float toL = fmaxf(1.f - x2, EPSf);     // = 2/lam at x = z_t
      float vls = toL * atanhf(fminf(wn, 1.f - 1e-6f)) / wn;
#pragma unroll
      for (int T = 0; T < 16; ++T) {
        float vl = vls * wd[T];
        vel[T] = fmaf(wt, vl, vel[T]);
        if (l4 == 0 && p < 3)
          VO[((size_t)p * NSEQ + sidx) * 256 + T * 16 + l15] = f2bf(vl);
      }
      wt *= (1.f / 0.9f);
    }
  }

  // vel all-reduce across the 4 groups
#pragma unroll
  for (int T = 0; T < 16; ++T) {
    vel[T] += __shfl_xor(vel[T], 16);
    vel[T] += __shfl_xor(vel[T], 32);
  }

  // outputs: z13 = group3 reg1
  if (l4 == 3) {
    float ynn = sqrtf(fmaxf(zn2_[1], 1e-14f));
    float gs = atanhf(fminf(ynn, 1.f - 1e-6f)) / ynn;
#pragma unroll
    for (int T = 0; T < 16; ++T) {
      int cidx = T * 16 + l15;
      float g = gs * z_[1][T];
      unsigned short gh = f2bf(g);
      Uh[(size_t)sidx * 512 + cidx] = gh;
      Ul[(size_t)sidx * 512 + cidx] = f2bf(g - bf2f(gh));
      ZL[(size_t)sidx * 256 + cidx] = z_[1][T];
    }
    if (l15 == 0) ZN2[sidx] = zn2_[1];
  }
  if (l4 == 0) {
#pragma unroll
    for (int T = 0; T < 16; ++T) {
      int cidx = T * 16 + l15;
      unsigned short vh = f2bf(vel[T]);
      Uh[(size_t)sidx * 512 + 256 + cidx] = vh;
      Ul[(size_t)sidx * 512 + 256 + cidx] = f2bf(vel[T] - bf2f(vh));
    }
  }
}

// ---------------- split-bf16 MFMA GEMM v2: 64x128 tile, BK=32, double-buffered, kg-XOR swizzle ----------------
// A: hi/lo bf16 planes, row-major M x lda. B: hi/lo tiled [K/8][N][8].
// EPI: 0 -> f32 out Cf; 1 -> tanh, split out Ch/Cl; 2 -> relu, split out Ch/Cl
template <int EPI>
__global__ __launch_bounds__(256) void gemm_split(
    const unsigned short* __restrict__ Ah, const unsigned short* __restrict__ Al, int lda, int K,
    const unsigned short* __restrict__ Bh, const unsigned short* __restrict__ Bl, int N,
    const float* __restrict__ bias,
    float* __restrict__ Cf, unsigned short* __restrict__ Ch, unsigned short* __restrict__ Cl, int ldc)
{
  __shared__ unsigned short As[2][2][4][64][8];    // [buf][plane][kg][m ^ (kg<<1)][8]
  __shared__ unsigned short Bs[2][2][4][128][8];   // [buf][plane][kg][n ^ (kg<<1)][8]
  const int tid = threadIdx.x;
  const int lane = tid & 63, wid = tid >> 6;
  const int wr = wid >> 1, wc = wid & 1;           // wave tile: rows wr*32..+32, cols wc*64..+64
  const int l15 = lane & 15, l4 = lane >> 4;
  const int row0 = blockIdx.x * 64, col0 = blockIdx.y * 128;

  // staging maps: A chunks (plane r, kg=tid&3, m=tid>>2); B chunks per round r:
  //   c = r*256+tid: n = c&127, kg = (c>>7)&3, plane = c>>9  (tid 0..127 -> consecutive n)
  const int a_kg = tid & 3, a_m = tid >> 2;

  uint4 ar[2], br[4];

  f32x4 acc[2][4];
#pragma unroll
  for (int i = 0; i < 2; ++i)
#pragma unroll
    for (int j = 0; j < 4; ++j) acc[i][j] = (f32x4){0.f, 0.f, 0.f, 0.f};

  const int nit = K >> 5;

  // prologue: load + write tile 0
#pragma unroll
  for (int r = 0; r < 2; ++r) {
    const unsigned short* basep = r ? Al : Ah;
    ar[r] = *(const uint4*)&basep[(size_t)(row0 + a_m) * lda + a_kg * 8];
  }
#pragma unroll
  for (int r = 0; r < 4; ++r) {
    int c = r * 256 + tid;
    int n = c & 127, kg = (c >> 7) & 3, plane = c >> 9;
    const unsigned short* basep = plane ? Bl : Bh;
    br[r] = *(const uint4*)&basep[((size_t)kg * N + col0 + n) * 8];
  }
#pragma unroll
  for (int r = 0; r < 2; ++r)
    *(uint4*)&As[0][r][a_kg][a_m ^ (a_kg << 1)][0] = ar[r];
#pragma unroll
  for (int r = 0; r < 4; ++r) {
    int c = r * 256 + tid;
    int n = c & 127, kg = (c >> 7) & 3, plane = c >> 9;
    *(uint4*)&Bs[0][plane][kg][n ^ (kg << 1)][0] = br[r];
  }
  __syncthreads();

  for (int it = 0; it < nit; ++it) {
    const int cur = it & 1;
    // issue next-tile global loads (hide under MFMA)
    if (it + 1 < nit) {
      const int k0 = (it + 1) << 5;
#pragma unroll
      for (int r = 0; r < 2; ++r) {
        const unsigned short* basep = r ? Al : Ah;
        ar[r] = *(const uint4*)&basep[(size_t)(row0 + a_m) * lda + k0 + a_kg * 8];
      }
#pragma unroll
      for (int r = 0; r < 4; ++r) {
        int c = r * 256 + tid;
        int n = c & 127, kg = (c >> 7) & 3, plane = c >> 9;
        const unsigned short* basep = plane ? Bl : Bh;
        br[r] = *(const uint4*)&basep[((size_t)((k0 >> 3) + kg) * N + col0 + n) * 8];
      }
    }

    // fragments from buf cur (swizzled rows) + MFMA
    bf16x8 fah[2], fal[2], fbh[4], fbl[4];
#pragma unroll
    for (int mi = 0; mi < 2; ++mi) {
      int rr = wr * 32 + mi * 16 + l15;
      fah[mi] = *(const bf16x8*)&As[cur][0][l4][rr ^ (l4 << 1)][0];
      fal[mi] = *(const bf16x8*)&As[cur][1][l4][rr ^ (l4 << 1)][0];
    }
#pragma unroll
    for (int ni = 0; ni < 4; ++ni) {
      int nn = wc * 64 + ni * 16 + l15;
      fbh[ni] = *(const bf16x8*)&Bs[cur][0][l4][nn ^ (l4 << 1)][0];
      fbl[ni] = *(const bf16x8*)&Bs[cur][1][l4][nn ^ (l4 << 1)][0];
    }
#pragma unroll
    for (int mi = 0; mi < 2; ++mi)
#pragma unroll
      for (int ni = 0; ni < 4; ++ni) {
        acc[mi][ni] = __builtin_amdgcn_mfma_f32_16x16x32_bf16(fah[mi], fbh[ni], acc[mi][ni], 0, 0, 0);
        acc[mi][ni] = __builtin_amdgcn_mfma_f32_16x16x32_bf16(fah[mi], fbl[ni], acc[mi][ni], 0, 0, 0);
        acc[mi][ni] = __builtin_amdgcn_mfma_f32_16x16x32_bf16(fal[mi], fbh[ni], acc[mi][ni], 0, 0, 0);
      }

    // write next tile into other buffer
    if (it + 1 < nit) {
      const int nxt = cur ^ 1;
#pragma unroll
      for (int r = 0; r < 2; ++r)
        *(uint4*)&As[nxt][r][a_kg][a_m ^ (a_kg << 1)][0] = ar[r];
#pragma unroll
      for (int r = 0; r < 4; ++r) {
        int c = r * 256 + tid;
        int n = c & 127, kg = (c >> 7) & 3, plane = c >> 9;
        *(uint4*)&Bs[nxt][plane][kg][n ^ (kg << 1)][0] = br[r];
      }
    }
    __syncthreads();
  }

#pragma unroll
  for (int mi = 0; mi < 2; ++mi)
#pragma unroll
    for (int ni = 0; ni < 4; ++ni) {
      int cc = col0 + wc * 64 + ni * 16 + l15;
      float bv = bias[cc];
      int rbase = row0 + wr * 32 + mi * 16 + l4 * 4;
#pragma unroll
      for (int r = 0; r < 4; ++r) {
        float v = acc[mi][ni][r] + bv;
        if (EPI == 1) v = tanhf(v);
        else if (EPI == 2) v = fmaxf(v, 0.f);
        if (EPI == 0) {
          Cf[(size_t)(rbase + r) * ldc + cc] = v;
        } else {
          unsigned short h = f2bf(v);
          Ch[(size_t)(rbase + r) * ldc + cc] = h;
          Cl[(size_t)(rbase + r) * ldc + cc] = f2bf(v - bf2f(h));
        }
      }
    }
}

// ---------------- per-sequence step (one WAVE per sequence), f32 scalars ----------------
__device__ __forceinline__ double wave_sum_d(double v) {
#pragma unroll
  for (int off = 32; off > 0; off >>= 1) v += __shfl_xor(v, off);
  return v;
}

__global__ __launch_bounds__(256) void step_kernel(
    const float* __restrict__ V, unsigned short* __restrict__ Uh, unsigned short* __restrict__ Ul,
    float* __restrict__ ZL, float* __restrict__ ZN2, const unsigned short* __restrict__ VOk, int k)
{
  const int tid = threadIdx.x, w = tid >> 6, lane = tid & 63;
  const int sidx = blockIdx.x * 4 + w;

  float x[4], v[4];
#pragma unroll
  for (int j = 0; j < 4; ++j) {
    x[j] = ZL[(size_t)sidx * 256 + lane + 64 * j];
    v[j] = V[(size_t)sidx * 256 + lane + 64 * j];
  }
  float x2 = ZN2[sidx];

  double sxv = 0.0, svv = 0.0;
#pragma unroll
  for (int j = 0; j < 4; ++j) {
    sxv += (double)x[j] * (double)v[j];
    svv += (double)v[j] * (double)v[j];
  }
  float xv = (float)wave_sum_d(sxv);
  float vn2 = (float)wave_sum_d(svv);
  float vn = sqrtf(fmaxf(vn2, 1e-14f));
  float twoOverLam = fmaxf(1.f - x2, EPSf);
  float th = tanhf(vn / twoOverLam);
  float sec_s = th / vn;
  float y2 = th * th;
  float xy = sec_s * xv;
  float den = fmaxf(1.f + 2.f * xy + x2 * y2, 1e-15f);
  float alpha = (1.f + 2.f * xy + y2) / den;
  float beta = (1.f - x2) * sec_s / den;

  float zn[4];
  double snn = 0.0;
#pragma unroll
  for (int j = 0; j < 4; ++j) {
    zn[j] = alpha * x[j] + beta * v[j];
    snn += (double)zn[j] * (double)zn[j];
  }
  float n2 = (float)wave_sum_d(snn);
  float n = sqrtf(fmaxf(n2, 1e-14f));
  bool clip = n > MAXN;
  float scl = clip ? MAXN / n : 1.f;
  float z2 = clip ? MAXN2 : n2;
#pragma unroll
  for (int j = 0; j < 4; ++j) {
    zn[j] *= scl;
    ZL[(size_t)sidx * 256 + lane + 64 * j] = zn[j];
  }
  if (lane == 0) ZN2[sidx] = z2;

  float ynn = sqrtf(fmaxf(z2, 1e-14f));
  float gs = atanhf(fminf(ynn, 1.f - 1e-6f)) / ynn;
#pragma unroll
  for (int j = 0; j < 4; ++j) {
    float g = gs * zn[j];
    unsigned short gh = f2bf(g);
    Uh[(size_t)sidx * 512 + lane + 64 * j] = gh;
    Ul[(size_t)sidx * 512 + lane + 64 * j] = f2bf(g - bf2f(gh));
  }

  if (k < 3) {
    float xy2 = scl * (alpha * x2 + beta * xv);
    float den2 = fmaxf(1.f - 2.f * xy2 + x2 * z2, 1e-15f);
    float a2 = (1.f - 2.f * xy2 + z2) / den2;
    float b2 = (1.f - x2) / den2;
    float wv[4];
    double sww = 0.0;
#pragma unroll
    for (int j = 0; j < 4; ++j) {
      wv[j] = b2 * zn[j] - a2 * x[j];
      sww += (double)wv[j] * (double)wv[j];
    }
    float wn2 = (float)wave_sum_d(sww);
    float wn = sqrtf(fmaxf(wn2, 1e-14f));
    float vls = twoOverLam * atanhf(fminf(wn, 1.f - 1e-6f)) / wn;

    float p12 = 1.f;
#pragma unroll
    for (int i = 0; i < 12; ++i) p12 *= 0.9f;
    float wsum = (1.f - p12 * 0.9f) / 0.1f;
    float w0 = p12 / wsum;
    float w12 = 1.f / wsum;
#pragma unroll
    for (int j = 0; j < 4; ++j) {
      int d = 256 + lane + 64 * j;
      float velold = bf2f(Uh[(size_t)sidx * 512 + d]) + bf2f(Ul[(size_t)sidx * 512 + d]);
      float vdrop = bf2f(VOk[(size_t)sidx * 256 + lane + 64 * j]);
      float velnew = 0.9f * (velold - w0 * vdrop) + w12 * (vls * wv[j]);
      unsigned short vh = f2bf(velnew);
      Uh[(size_t)sidx * 512 + d] = vh;
      Ul[(size_t)sidx * 512 + d] = f2bf(velnew - bf2f(vh));
    }
  }
}

// ---------------- GEMM4 (MFMA): r = R1(20480x512) @ Wr2(512x24->32) + br2, scattered write ----------------
__global__ __launch_bounds__(256) void gemm4_mfma(
    const unsigned short* __restrict__ Ah, const unsigned short* __restrict__ Al,
    const unsigned short* __restrict__ Bh, const unsigned short* __restrict__ Bl,
    const float* __restrict__ br2, float* __restrict__ out, int step)
{
  __shared__ unsigned short As[2][4][128][8];
  __shared__ unsigned short Bs[2][4][32][8];
  const int tid = threadIdx.x, lane = tid & 63, wid = tid >> 6;
  const int l15 = lane & 15, l4 = lane >> 4;
  const int row0 = blockIdx.x * 128;

  f32x4 acc[2][2];
#pragma unroll
  for (int i = 0; i < 2; ++i)
#pragma unroll
    for (int j = 0; j < 2; ++j) acc[i][j] = (f32x4){0.f, 0.f, 0.f, 0.f};

  const int sm = tid >> 2, skg = tid & 3;
  const int bplane = tid >> 7, bc = tid & 127, bkg = bc >> 5, bnn = bc & 31;
  const unsigned short* Bp = bplane ? Bl : Bh;

  for (int k0 = 0; k0 < 512; k0 += 32) {
    size_t abase = (size_t)(row0 + sm) * 512 + k0 + skg * 8;
    *(uint4*)&As[0][skg][sm][0] = *(const uint4*)&Ah[abase];
    *(uint4*)&As[1][skg][sm][0] = *(const uint4*)&Al[abase];
    size_t abase2 = abase + (size_t)64 * 512;
    *(uint4*)&As[0][skg][sm + 64][0] = *(const uint4*)&Ah[abase2];
    *(uint4*)&As[1][skg][sm + 64][0] = *(const uint4*)&Al[abase2];
    size_t bbase = ((size_t)((k0 >> 3) + bkg) * 32 + bnn) * 8;
    *(uint4*)&Bs[bplane][bkg][bnn][0] = *(const uint4*)&Bp[bbase];
    __syncthreads();

    bf16x8 fah[2], fal[2], fbh[2], fbl[2];
#pragma unroll
    for (int mi = 0; mi < 2; ++mi) {
      fah[mi] = *(const bf16x8*)&As[0][l4][wid * 32 + mi * 16 + l15][0];
      fal[mi] = *(const bf16x8*)&As[1][l4][wid * 32 + mi * 16 + l15][0];
    }
#pragma unroll
    for (int ni = 0; ni < 2; ++ni) {
      fbh[ni] = *(const bf16x8*)&Bs[0][l4][ni * 16 + l15][0];
      fbl[ni] = *(const bf16x8*)&Bs[1][l4][ni * 16 + l15][0];
    }
#pragma unroll
    for (int mi = 0; mi < 2; ++mi)
#pragma unroll
      for (int ni = 0; ni < 2; ++ni) {
        acc[mi][ni] = __builtin_amdgcn_mfma_f32_16x16x32_bf16(fah[mi], fbh[ni], acc[mi][ni], 0, 0, 0);
        acc[mi][ni] = __builtin_amdgcn_mfma_f32_16x16x32_bf16(fah[mi], fbl[ni], acc[mi][ni], 0, 0, 0);
        acc[mi][ni] = __builtin_amdgcn_mfma_f32_16x16x32_bf16(fal[mi], fbh[ni], acc[mi][ni], 0, 0, 0);
      }
    __syncthreads();
  }

#pragma unroll
  for (int mi = 0; mi < 2; ++mi)
#pragma unroll
    for (int ni = 0; ni < 2; ++ni) {
      int j = ni * 16 + l15;
      if (j < 24) {
        float bv = br2[j];
#pragma unroll
        for (int r = 0; r < 4; ++r) {
          int row = row0 + wid * 32 + mi * 16 + l4 * 4 + r;
          int c = row >> 12, bf = row & 4095, b = bf >> 6, f = bf & 63;
          size_t base = (((size_t)(c * 64 + b) * 96) + (size_t)step * 24 + j) * 64 + f;
          out[base] = acc[mi][ni][r] + bv;
        }
      }
    }
}

extern "C" void kernel_launch(void* const* d_in, const int* in_sizes, int n_in,
                              void* d_out, int out_size, void* d_ws, size_t ws_size,
                              hipStream_t stream)
{
  const float* trend  = (const float*)d_in[0];
  const float* coarse = (const float*)d_in[1];
  const float* fine   = (const float*)d_in[2];
  const float* resid  = (const float*)d_in[3];
  const float* W_emb  = (const float*)d_in[4];
  const float* b_emb  = (const float*)d_in[5];
  const float* W1  = (const float*)d_in[6];
  const float* b1  = (const float*)d_in[7];
  const float* W2  = (const float*)d_in[8];
  const float* b2  = (const float*)d_in[9];
  const float* Wr1 = (const float*)d_in[10];
  const float* br1 = (const float*)d_in[11];
  const float* Wr2 = (const float*)d_in[12];
  const float* br2 = (const float*)d_in[13];
  float* out = (float*)d_out;

  char* p = (char*)d_ws;
  size_t off = 0;
  auto alloc = [&](size_t bytes) -> void* {
    void* r = p + off;
    off = (off + bytes + 255) & ~(size_t)255;
    return r;
  };
  unsigned short* Uh = (unsigned short*)alloc((size_t)NSEQ * 512 * 2);
  unsigned short* Ul = (unsigned short*)alloc((size_t)NSEQ * 512 * 2);
  unsigned short* Hh = (unsigned short*)alloc((size_t)NSEQ * 512 * 2);
  unsigned short* Hl = (unsigned short*)alloc((size_t)NSEQ * 512 * 2);
  float* V   = (float*)alloc((size_t)NSEQ * 256 * 4);
  float* ZL  = (float*)alloc((size_t)NSEQ * 256 * 4);
  float* ZN2 = (float*)alloc((size_t)NSEQ * 4);
  unsigned short* VO = (unsigned short*)alloc((size_t)3 * NSEQ * 256 * 2);
  float* XT  = (float*)alloc((size_t)5 * 4096 * 336 * 4);
  unsigned short* W1h = (unsigned short*)alloc((size_t)512 * 512 * 2);
  unsigned short* W1l = (unsigned short*)alloc((size_t)512 * 512 * 2);
  unsigned short* W2h = (unsigned short*)alloc((size_t)512 * 256 * 2);
  unsigned short* W2l = (unsigned short*)alloc((size_t)512 * 256 * 2);
  unsigned short* Wr1h = (unsigned short*)alloc((size_t)256 * 512 * 2);
  unsigned short* Wr1l = (unsigned short*)alloc((size_t)256 * 512 * 2);
  unsigned short* Wr2h = (unsigned short*)alloc((size_t)512 * 32 * 2);
  unsigned short* Wr2l = (unsigned short*)alloc((size_t)512 * 32 * 2);
  unsigned short* WgH = (unsigned short*)alloc((size_t)16 * 64 * 8 * 2);
  unsigned short* WgL = (unsigned short*)alloc((size_t)16 * 64 * 8 * 2);

  fold_transpose<<<dim3(64, 6), 256, 0, stream>>>(trend, coarse, fine, resid, XT);
  conv_weight<<<(512 * 512 + 255) / 256, 256, 0, stream>>>(W1, W1h, W1l, 512, 512, 512);
  conv_weight<<<(512 * 256 + 255) / 256, 256, 0, stream>>>(W2, W2h, W2l, 512, 256, 256);
  conv_weight<<<(256 * 512 + 255) / 256, 256, 0, stream>>>(Wr1, Wr1h, Wr1l, 256, 512, 512);
  conv_weight<<<(512 * 32 + 255) / 256, 256, 0, stream>>>(Wr2, Wr2h, Wr2l, 512, 32, 24);
  conv_wemb<<<32, 256, 0, stream>>>(W_emb, WgH, WgL);
  init_kernel<<<NSEQ / 4, 256, 0, stream>>>(XT, WgH, WgL, b_emb, Uh, Ul, ZL, ZN2, VO);

  for (int k = 0; k < 4; ++k) {
    // H = tanh(U @ W1 + b1)   (20480x512)@(512x512)
    gemm_split<1><<<dim3(320, 4), 256, 0, stream>>>(Uh, Ul, 512, 512, W1h, W1l, 512, b1,
                                                    nullptr, Hh, Hl, 512);
    // V = H @ W2 + b2         (20480x512)@(512x256)
    gemm_split<0><<<dim3(320, 2), 256, 0, stream>>>(Hh, Hl, 512, 512, W2h, W2l, 256, b2,
                                                    V, nullptr, nullptr, 256);
    const unsigned short* vok = VO + (size_t)(k < 3 ? k : 0) * NSEQ * 256;
    step_kernel<<<NSEQ / 4, 256, 0, stream>>>(V, Uh, Ul, ZL, ZN2, vok, k);
    // R1 = relu(U[:,0:256] @ Wr1 + br1)  (20480x256)@(256x512)
    gemm_split<2><<<dim3(320, 4), 256, 0, stream>>>(Uh, Ul, 512, 256, Wr1h, Wr1l, 512, br1,
                                                    nullptr, Hh, Hl, 512);
    // out slice = R1 @ Wr2 + br2
    gemm4_mfma<<<160, 256, 0, stream>>>(Hh, Hl, Wr2h, Wr2l, br2, out, k);
  }
}

// Round 8
// 782.854 us; speedup vs baseline: 1.9160x; 1.9160x over previous
//
#include <hip/hip_runtime.h>
#include <cstddef>

#define NSEQ 20480
#define EPSf 1e-7f
#define MAXN 0.99999f
#define MAXN2 (0.99999f * 0.99999f)

typedef __attribute__((ext_vector_type(8))) short bf16x8;
typedef __attribute__((ext_vector_type(4))) float f32x4;

__device__ __forceinline__ unsigned short f2bf(float x) {
  unsigned u = __float_as_uint(x);
  u += 0x7FFF + ((u >> 16) & 1);
  return (unsigned short)(u >> 16);
}
__device__ __forceinline__ float bf2f(unsigned short h) {
  return __uint_as_float(((unsigned)h) << 16);
}
// async global->LDS, 16B/lane; dst wave-uniform base (HW adds lane*16), src per-lane
__device__ __forceinline__ void gload16(const void* g, void* l) {
  __builtin_amdgcn_global_load_lds(
      (const __attribute__((address_space(1))) void*)g,
      (__attribute__((address_space(3))) void*)l, 16, 0, 0);
}

// Activation tiled layout (same as weights): act[kg][m][e], kg=k>>3, e=k&7
// addr = (kg*NSEQ + m)*8 + e

// ---------------- fold transpose: X[b][l][f] (4 arrays) -> XT[ch][b*64+f][l], ch0 = sum ----------------
__global__ __launch_bounds__(256) void fold_transpose(
    const float* __restrict__ t, const float* __restrict__ c,
    const float* __restrict__ f, const float* __restrict__ r,
    float* __restrict__ XT)
{
  __shared__ float tile[4][56][65];
  const int b = blockIdx.x, l0 = blockIdx.y * 56;
  const int tid = threadIdx.x;
  const int fi = tid & 63, lr0 = tid >> 6;
#pragma unroll
  for (int i = 0; i < 14; ++i) {
    int lr = lr0 + i * 4;
    size_t idx = ((size_t)b * 336 + l0 + lr) * 64 + fi;
    tile[0][lr][fi] = t[idx];
    tile[1][lr][fi] = c[idx];
    tile[2][lr][fi] = f[idx];
    tile[3][lr][fi] = r[idx];
  }
  __syncthreads();
#pragma unroll
  for (int ch = 0; ch < 5; ++ch) {
    for (int i = 0; i < 14; ++i) {
      int idx2 = i * 256 + tid;
      int ff = idx2 / 56, ll = idx2 % 56;
      float v;
      if (ch == 0) v = tile[0][ll][ff] + tile[1][ll][ff] + tile[2][ll][ff] + tile[3][ll][ff];
      else v = tile[ch - 1][ll][ff];
      XT[((size_t)ch * 4096 + (b << 6) + ff) * 336 + l0 + ll] = v;
    }
  }
}

// ---------------- weight split+tile: W[k][n] f32 -> Wh/Wl bf16 at [(k>>3)*N + n]*8 + (k&7) ----------------
__global__ __launch_bounds__(256) void conv_weight(
    const float* __restrict__ W, unsigned short* __restrict__ Wh, unsigned short* __restrict__ Wl,
    int K, int N, int Nsrc)
{
  int idx = blockIdx.x * 256 + threadIdx.x;
  if (idx >= K * N) return;
  int k = idx / N, n = idx % N;
  float x = (n < Nsrc) ? W[(size_t)k * Nsrc + n] : 0.f;
  unsigned short h = f2bf(x);
  size_t o = ((size_t)(k >> 3) * N + n) * 8 + (k & 7);
  Wh[o] = h;
  Wl[o] = f2bf(x - bf2f(h));
}

// ---------------- W_emb -> MFMA B-fragment layout: Wg[T][lane][j], k=8*(lane>>4)+j, n=T*16+(lane&15) ----------------
__global__ __launch_bounds__(256) void conv_wemb(
    const float* __restrict__ W_emb, unsigned short* __restrict__ WgH, unsigned short* __restrict__ WgL)
{
  int idx = blockIdx.x * 256 + threadIdx.x;
  if (idx >= 16 * 64 * 8) return;
  int j = idx & 7, ln = (idx >> 3) & 63, T = idx >> 9;
  int k = 8 * (ln >> 4) + j, n = T * 16 + (ln & 15);
  float x = (k < 24) ? W_emb[(size_t)k * 256 + n] : 0.f;
  unsigned short h = f2bf(x);
  WgH[idx] = h;
  WgL[idx] = f2bf(x - bf2f(h));
}

// ---------------- init: MFMA embed + expmap0 + parallel velocity pairs, one WAVE per sequence ----------------
__global__ __launch_bounds__(256) void init_kernel(
    const float* __restrict__ XT,
    const unsigned short* __restrict__ WgH, const unsigned short* __restrict__ WgL,
    const float* __restrict__ b_emb,
    unsigned short* __restrict__ Uh, unsigned short* __restrict__ Ul,
    float* __restrict__ ZL, float* __restrict__ ZN2, unsigned short* __restrict__ VO)
{
  __shared__ unsigned short Bsh[2][16][64][8];   // 32 KB, shared by 4 waves
  __shared__ float segs[4][384];
  __shared__ float bsh[256];
  const int tid = threadIdx.x, w = tid >> 6, lane = tid & 63;
  const int l15 = lane & 15, l4 = lane >> 4;
  const int sidx = blockIdx.x * 4 + w;

  {
    const uint4* srcH = (const uint4*)WgH;       // 8192 shorts = 16384 B = 1024 uint4
    uint4* dstH = (uint4*)&Bsh[0][0][0][0];
    for (int i = tid; i < 1024; i += 256) dstH[i] = srcH[i];
    const uint4* srcL = (const uint4*)WgL;
    uint4* dstL = (uint4*)&Bsh[1][0][0][0];
    for (int i = tid; i < 1024; i += 256) dstL[i] = srcL[i];
    bsh[tid] = b_emb[tid];
  }
  const float* src = XT + (size_t)sidx * 336;
  for (int l = lane; l < 336; l += 64) segs[w][l] = src[l];
  for (int l = 336 + lane; l < 384; l += 64) segs[w][l] = 0.f;
  __syncthreads();

  bf16x8 ah, al;
  if (l4 < 3) {
    const float* sp = &segs[w][l15 * 24 + l4 * 8];
    float4 q0 = *(const float4*)sp;
    float4 q1 = *(const float4*)(sp + 4);
    float vv[8] = {q0.x, q0.y, q0.z, q0.w, q1.x, q1.y, q1.z, q1.w};
#pragma unroll
    for (int j = 0; j < 8; ++j) {
      unsigned short h = f2bf(vv[j]);
      ah[j] = (short)h;
      al[j] = (short)f2bf(vv[j] - bf2f(h));
    }
  } else {
#pragma unroll
    for (int j = 0; j < 8; ++j) { ah[j] = 0; al[j] = 0; }
  }

  f32x4 acc[16];
#pragma unroll
  for (int T = 0; T < 16; ++T) acc[T] = (f32x4){0.f, 0.f, 0.f, 0.f};
#pragma unroll
  for (int T = 0; T < 16; ++T) {
    bf16x8 bh = *(const bf16x8*)&Bsh[0][T][lane][0];
    bf16x8 bl = *(const bf16x8*)&Bsh[1][T][lane][0];
    acc[T] = __builtin_amdgcn_mfma_f32_16x16x32_bf16(ah, bh, acc[T], 0, 0, 0);
    acc[T] = __builtin_amdgcn_mfma_f32_16x16x32_bf16(ah, bl, acc[T], 0, 0, 0);
    acc[T] = __builtin_amdgcn_mfma_f32_16x16x32_bf16(al, bh, acc[T], 0, 0, 0);
  }

  float z_[4][16];
  float zn2_[4];
  float ls[4] = {0.f, 0.f, 0.f, 0.f};
#pragma unroll
  for (int T = 0; T < 16; ++T) {
    float b = bsh[T * 16 + l15];
#pragma unroll
    for (int r = 0; r < 4; ++r) {
      float e = tanhf(acc[T][r] + b);
      z_[r][T] = e;
      ls[r] = fmaf(e, e, ls[r]);
    }
  }
#pragma unroll
  for (int m = 1; m < 16; m <<= 1)
#pragma unroll
    for (int r = 0; r < 4; ++r) ls[r] += __shfl_xor(ls[r], m);
#pragma unroll
  for (int r = 0; r < 4; ++r) {
    float vn = sqrtf(fmaxf(ls[r], 1e-14f));
    float tt = tanhf(vn);
    bool clip = tt > MAXN;
    float scale = (clip ? MAXN : tt) / vn;
#pragma unroll
    for (int T = 0; T < 16; ++T) z_[r][T] *= scale;
    zn2_[r] = clip ? MAXN2 : tt * tt;
  }

  float zsh[16], zn2sh;
#pragma unroll
  for (int T = 0; T < 16; ++T) zsh[T] = __shfl(z_[0][T], (lane + 16) & 63);
  zn2sh = __shfl(zn2_[0], (lane + 16) & 63);

  float vel[16];
#pragma unroll
  for (int T = 0; T < 16; ++T) vel[T] = 0.f;
  const float p4c = 0.9f * 0.9f * 0.9f * 0.9f;
  const float p8c = p4c * p4c, p12c = p8c * p4c;
  const float wsum = (1.f - p12c * 0.9f) / 0.1f;
  float wt = ((l4 == 0) ? p12c : (l4 == 1) ? p8c : (l4 == 2) ? p4c : 1.f) / wsum;
  const int npairs = (l4 < 3) ? 4 : 1;
#pragma unroll
  for (int p = 0; p < 4; ++p) {
    if (p < npairs) {
      double sxy = 0.0;
#pragma unroll
      for (int T = 0; T < 16; ++T) {
        float zt1 = (p < 3) ? z_[(p + 1) & 3][T] : zsh[T];
        sxy += (double)z_[p][T] * (double)zt1;
      }
#pragma unroll
      for (int m = 1; m < 16; m <<= 1) sxy += __shfl_xor(sxy, m);
      float x2 = zn2_[p];
      float y2 = (p < 3) ? zn2_[(p + 1) & 3] : zn2sh;
      float xy = (float)sxy;
      float den = fmaxf(1.f - 2.f * xy + x2 * y2, 1e-15f);
      float a2 = (1.f - 2.f * xy + y2) / den;
      float b2c = (1.f - x2) / den;
      float wd[16];
      float sww = 0.f;
#pragma unroll
      for (int T = 0; T < 16; ++T) {
        float zt1 = (p < 3) ? z_[(p + 1) & 3][T] : zsh[T];
        wd[T] = b2c * zt1 - a2 * z_[p][T];
        sww = fmaf(wd[T], wd[T], sww);
      }
#pragma unroll
      for (int m = 1; m < 16; m <<= 1) sww += __shfl_xor(sww, m);
      float wn = sqrtf(fmaxf(sww, 1e-14f));
      float toL = fmaxf(1.f - x2, EPSf);
      float vls = toL * atanhf(fminf(wn, 1.f - 1e-6f)) / wn;
#pragma unroll
      for (int T = 0; T < 16; ++T) {
        float vl = vls * wd[T];
        vel[T] = fmaf(wt, vl, vel[T]);
        if (l4 == 0 && p < 3)
          VO[((size_t)p * NSEQ + sidx) * 256 + T * 16 + l15] = f2bf(vl);
      }
      wt *= (1.f / 0.9f);
    }
  }

#pragma unroll
  for (int T = 0; T < 16; ++T) {
    vel[T] += __shfl_xor(vel[T], 16);
    vel[T] += __shfl_xor(vel[T], 32);
  }

  // outputs in tiled layout: U[kg][m][e]
  if (l4 == 3) {
    float ynn = sqrtf(fmaxf(zn2_[1], 1e-14f));
    float gs = atanhf(fminf(ynn, 1.f - 1e-6f)) / ynn;
#pragma unroll
    for (int T = 0; T < 16; ++T) {
      int cidx = T * 16 + l15;
      float g = gs * z_[1][T];
      unsigned short gh = f2bf(g);
      size_t o = ((size_t)(cidx >> 3) * NSEQ + sidx) * 8 + (cidx & 7);
      Uh[o] = gh;
      Ul[o] = f2bf(g - bf2f(gh));
      ZL[(size_t)sidx * 256 + cidx] = z_[1][T];
    }
    if (l15 == 0) ZN2[sidx] = zn2_[1];
  }
  if (l4 == 0) {
#pragma unroll
    for (int T = 0; T < 16; ++T) {
      int cidx = 256 + T * 16 + l15;
      unsigned short vh = f2bf(vel[T]);
      size_t o = ((size_t)(cidx >> 3) * NSEQ + sidx) * 8 + (cidx & 7);
      Uh[o] = vh;
      Ul[o] = f2bf(vel[T] - bf2f(vh));
    }
  }
}

// ---------------- split-bf16 MFMA GEMM: 128x128 tile, BK=32, global_load_lds staging ----------------
// A: hi/lo tiled [K/8][NSEQ][8]. B: hi/lo tiled [K/8][N][8].
// EPI: 0 -> f32 out Cf (row-major ldc); 1 -> tanh, split tiled out; 2 -> relu, split tiled out
template <int EPI>
__global__ __launch_bounds__(256) void gemm_split(
    const unsigned short* __restrict__ Ah, const unsigned short* __restrict__ Al, int K,
    const unsigned short* __restrict__ Bh, const unsigned short* __restrict__ Bl, int N,
    const float* __restrict__ bias,
    float* __restrict__ Cf, unsigned short* __restrict__ Ch, unsigned short* __restrict__ Cl, int ldc)
{
  __shared__ unsigned short As[2][4][128][8];    // chunk c = plane*512 + kg*128 + m
  __shared__ unsigned short Bs[2][4][128][8];    // chunk c = plane*512 + kg*128 + n
  const int tid = threadIdx.x;
  const int lane = tid & 63, wid = tid >> 6;
  const int wr = wid >> 1, wc = wid & 1;
  const int l15 = lane & 15, l4 = lane >> 4;
  const int row0 = blockIdx.x * 128, col0 = blockIdx.y * 128;
  unsigned short* As_flat = &As[0][0][0][0];
  unsigned short* Bs_flat = &Bs[0][0][0][0];

  f32x4 acc[4][4];
#pragma unroll
  for (int i = 0; i < 4; ++i)
#pragma unroll
    for (int j = 0; j < 4; ++j) acc[i][j] = (f32x4){0.f, 0.f, 0.f, 0.f};

  for (int k0 = 0; k0 < K; k0 += 32) {
    const int kb = k0 >> 3;
#pragma unroll
    for (int rd = 0; rd < 4; ++rd) {
      int c = rd * 256 + tid;                    // lanes -> consecutive m (contiguous 16B chunks)
      int plane = c >> 9, rem = c & 511;
      int kg = rem >> 7, m = rem & 127;
      const unsigned short* srcp = (plane ? Al : Ah) + ((size_t)(kb + kg) * NSEQ + row0 + m) * 8;
      gload16(srcp, As_flat + (size_t)(rd * 256 + wid * 64) * 8);
    }
#pragma unroll
    for (int rd = 0; rd < 4; ++rd) {
      int c = rd * 256 + tid;                    // lanes -> consecutive n (contiguous 16B chunks)
      int plane = c >> 9, rem = c & 511;
      int kg = rem >> 7, n = rem & 127;
      const unsigned short* srcp = (plane ? Bl : Bh) + ((size_t)(kb + kg) * N + col0 + n) * 8;
      gload16(srcp, Bs_flat + (size_t)(rd * 256 + wid * 64) * 8);
    }
    __syncthreads();

    bf16x8 fah[4], fal[4], fbh[4], fbl[4];
#pragma unroll
    for (int mi = 0; mi < 4; ++mi) {
      fah[mi] = *(const bf16x8*)&As[0][l4][wr * 64 + mi * 16 + l15][0];
      fal[mi] = *(const bf16x8*)&As[1][l4][wr * 64 + mi * 16 + l15][0];
    }
#pragma unroll
    for (int ni = 0; ni < 4; ++ni) {
      fbh[ni] = *(const bf16x8*)&Bs[0][l4][wc * 64 + ni * 16 + l15][0];
      fbl[ni] = *(const bf16x8*)&Bs[1][l4][wc * 64 + ni * 16 + l15][0];
    }
#pragma unroll
    for (int mi = 0; mi < 4; ++mi)
#pragma unroll
      for (int ni = 0; ni < 4; ++ni) {
        acc[mi][ni] = __builtin_amdgcn_mfma_f32_16x16x32_bf16(fah[mi], fbh[ni], acc[mi][ni], 0, 0, 0);
        acc[mi][ni] = __builtin_amdgcn_mfma_f32_16x16x32_bf16(fah[mi], fbl[ni], acc[mi][ni], 0, 0, 0);
        acc[mi][ni] = __builtin_amdgcn_mfma_f32_16x16x32_bf16(fal[mi], fbh[ni], acc[mi][ni], 0, 0, 0);
      }
    __syncthreads();
  }

#pragma unroll
  for (int mi = 0; mi < 4; ++mi)
#pragma unroll
    for (int ni = 0; ni < 4; ++ni) {
      int cc = col0 + wc * 64 + ni * 16 + l15;
      float bv = bias[cc];
      int rbase = row0 + wr * 64 + mi * 16 + l4 * 4;
#pragma unroll
      for (int r = 0; r < 4; ++r) {
        float v = acc[mi][ni][r] + bv;
        if (EPI == 1) v = tanhf(v);
        else if (EPI == 2) v = fmaxf(v, 0.f);
        if (EPI == 0) {
          Cf[(size_t)(rbase + r) * ldc + cc] = v;
        } else {
          unsigned short h = f2bf(v);
          size_t o = ((size_t)(cc >> 3) * NSEQ + rbase + r) * 8 + (cc & 7);
          Ch[o] = h;
          Cl[o] = f2bf(v - bf2f(h));
        }
      }
    }
}

// ---------------- per-sequence step (one WAVE per sequence), f32 scalars ----------------
__device__ __forceinline__ double wave_sum_d(double v) {
#pragma unroll
  for (int off = 32; off > 0; off >>= 1) v += __shfl_xor(v, off);
  return v;
}

__global__ __launch_bounds__(256) void step_kernel(
    const float* __restrict__ V, unsigned short* __restrict__ Uh, unsigned short* __restrict__ Ul,
    float* __restrict__ ZL, float* __restrict__ ZN2, const unsigned short* __restrict__ VOk, int k)
{
  const int tid = threadIdx.x, w = tid >> 6, lane = tid & 63;
  const int sidx = blockIdx.x * 4 + w;

  float x[4], v[4];
#pragma unroll
  for (int j = 0; j < 4; ++j) {
    x[j] = ZL[(size_t)sidx * 256 + lane + 64 * j];
    v[j] = V[(size_t)sidx * 256 + lane + 64 * j];
  }
  float x2 = ZN2[sidx];

  double sxv = 0.0, svv = 0.0;
#pragma unroll
  for (int j = 0; j < 4; ++j) {
    sxv += (double)x[j] * (double)v[j];
    svv += (double)v[j] * (double)v[j];
  }
  float xv = (float)wave_sum_d(sxv);
  float vn2 = (float)wave_sum_d(svv);
  float vn = sqrtf(fmaxf(vn2, 1e-14f));
  float twoOverLam = fmaxf(1.f - x2, EPSf);
  float th = tanhf(vn / twoOverLam);
  float sec_s = th / vn;
  float y2 = th * th;
  float xy = sec_s * xv;
  float den = fmaxf(1.f + 2.f * xy + x2 * y2, 1e-15f);
  float alpha = (1.f + 2.f * xy + y2) / den;
  float beta = (1.f - x2) * sec_s / den;

  float zn[4];
  double snn = 0.0;
#pragma unroll
  for (int j = 0; j < 4; ++j) {
    zn[j] = alpha * x[j] + beta * v[j];
    snn += (double)zn[j] * (double)zn[j];
  }
  float n2 = (float)wave_sum_d(snn);
  float n = sqrtf(fmaxf(n2, 1e-14f));
  bool clip = n > MAXN;
  float scl = clip ? MAXN / n : 1.f;
  float z2 = clip ? MAXN2 : n2;
#pragma unroll
  for (int j = 0; j < 4; ++j) {
    zn[j] *= scl;
    ZL[(size_t)sidx * 256 + lane + 64 * j] = zn[j];
  }
  if (lane == 0) ZN2[sidx] = z2;

  float ynn = sqrtf(fmaxf(z2, 1e-14f));
  float gs = atanhf(fminf(ynn, 1.f - 1e-6f)) / ynn;
#pragma unroll
  for (int j = 0; j < 4; ++j) {
    int d = lane + 64 * j;
    float g = gs * zn[j];
    unsigned short gh = f2bf(g);
    size_t o = ((size_t)(d >> 3) * NSEQ + sidx) * 8 + (d & 7);
    Uh[o] = gh;
    Ul[o] = f2bf(g - bf2f(gh));
  }

  if (k < 3) {
    float xy2 = scl * (alpha * x2 + beta * xv);
    float den2 = fmaxf(1.f - 2.f * xy2 + x2 * z2, 1e-15f);
    float a2 = (1.f - 2.f * xy2 + z2) / den2;
    float b2 = (1.f - x2) / den2;
    float wv[4];
    double sww = 0.0;
#pragma unroll
    for (int j = 0; j < 4; ++j) {
      wv[j] = b2 * zn[j] - a2 * x[j];
      sww += (double)wv[j] * (double)wv[j];
    }
    float wn2 = (float)wave_sum_d(sww);
    float wn = sqrtf(fmaxf(wn2, 1e-14f));
    float vls = twoOverLam * atanhf(fminf(wn, 1.f - 1e-6f)) / wn;

    float p12 = 1.f;
#pragma unroll
    for (int i = 0; i < 12; ++i) p12 *= 0.9f;
    float wsum = (1.f - p12 * 0.9f) / 0.1f;
    float w0 = p12 / wsum;
    float w12 = 1.f / wsum;
#pragma unroll
    for (int j = 0; j < 4; ++j) {
      int dd = 256 + lane + 64 * j;
      size_t o = ((size_t)(dd >> 3) * NSEQ + sidx) * 8 + (dd & 7);
      float velold = bf2f(Uh[o]) + bf2f(Ul[o]);
      float vdrop = bf2f(VOk[(size_t)sidx * 256 + lane + 64 * j]);
      float velnew = 0.9f * (velold - w0 * vdrop) + w12 * (vls * wv[j]);
      unsigned short vh = f2bf(velnew);
      Uh[o] = vh;
      Ul[o] = f2bf(velnew - bf2f(vh));
    }
  }
}

// ---------------- GEMM4 (MFMA): r = R1(20480x512 tiled) @ Wr2(512x24->32) + br2, scattered write ----------------
__global__ __launch_bounds__(256) void gemm4_mfma(
    const unsigned short* __restrict__ Ah, const unsigned short* __restrict__ Al,
    const unsigned short* __restrict__ Bh, const unsigned short* __restrict__ Bl,
    const float* __restrict__ br2, float* __restrict__ out, int step)
{
  __shared__ unsigned short As[2][4][128][8];
  __shared__ unsigned short Bs[2][4][32][8];     // chunk c = plane*128 + kg*32 + n
  const int tid = threadIdx.x, lane = tid & 63, wid = tid >> 6;
  const int l15 = lane & 15, l4 = lane >> 4;
  const int row0 = blockIdx.x * 128;
  unsigned short* As_flat = &As[0][0][0][0];
  unsigned short* Bs_flat = &Bs[0][0][0][0];

  f32x4 acc[2][2];
#pragma unroll
  for (int i = 0; i < 2; ++i)
#pragma unroll
    for (int j = 0; j < 2; ++j) acc[i][j] = (f32x4){0.f, 0.f, 0.f, 0.f};

  for (int k0 = 0; k0 < 512; k0 += 32) {
    const int kb = k0 >> 3;
#pragma unroll
    for (int rd = 0; rd < 4; ++rd) {
      int c = rd * 256 + tid;
      int plane = c >> 9, rem = c & 511;
      int kg = rem >> 7, m = rem & 127;
      const unsigned short* srcp = (plane ? Al : Ah) + ((size_t)(kb + kg) * NSEQ + row0 + m) * 8;
      gload16(srcp, As_flat + (size_t)(rd * 256 + wid * 64) * 8);
    }
    {
      int c = tid;                                // 256 chunks, 1 round; lanes contiguous
      int plane = c >> 7, rem = c & 127;
      int kg = rem >> 5, n = rem & 31;
      const unsigned short* srcp = (plane ? Bl : Bh) + ((size_t)(kb + kg) * 32 + n) * 8;
      gload16(srcp, Bs_flat + (size_t)(wid * 64) * 8);
    }
    __syncthreads();

    bf16x8 fah[2], fal[2], fbh[2], fbl[2];
#pragma unroll
    for (int mi = 0; mi < 2; ++mi) {
      fah[mi] = *(const bf16x8*)&As[0][l4][wid * 32 + mi * 16 + l15][0];
      fal[mi] = *(const bf16x8*)&As[1][l4][wid * 32 + mi * 16 + l15][0];
    }
#pragma unroll
    for (int ni = 0; ni < 2; ++ni) {
      fbh[ni] = *(const bf16x8*)&Bs[0][l4][ni * 16 + l15][0];
      fbl[ni] = *(const bf16x8*)&Bs[1][l4][ni * 16 + l15][0];
    }
#pragma unroll
    for (int mi = 0; mi < 2; ++mi)
#pragma unroll
      for (int ni = 0; ni < 2; ++ni) {
        acc[mi][ni] = __builtin_amdgcn_mfma_f32_16x16x32_bf16(fah[mi], fbh[ni], acc[mi][ni], 0, 0, 0);
        acc[mi][ni] = __builtin_amdgcn_mfma_f32_16x16x32_bf16(fah[mi], fbl[ni], acc[mi][ni], 0, 0, 0);
        acc[mi][ni] = __builtin_amdgcn_mfma_f32_16x16x32_bf16(fal[mi], fbh[ni], acc[mi][ni], 0, 0, 0);
      }
    __syncthreads();
  }

#pragma unroll
  for (int mi = 0; mi < 2; ++mi)
#pragma unroll
    for (int ni = 0; ni < 2; ++ni) {
      int j = ni * 16 + l15;
      if (j < 24) {
        float bv = br2[j];
#pragma unroll
        for (int r = 0; r < 4; ++r) {
          int row = row0 + wid * 32 + mi * 16 + l4 * 4 + r;
          int c = row >> 12, bf = row & 4095, b = bf >> 6, f = bf & 63;
          size_t base = (((size_t)(c * 64 + b) * 96) + (size_t)step * 24 + j) * 64 + f;
          out[base] = acc[mi][ni][r] + bv;
        }
      }
    }
}

extern "C" void kernel_launch(void* const* d_in, const int* in_sizes, int n_in,
                              void* d_out, int out_size, void* d_ws, size_t ws_size,
                              hipStream_t stream)
{
  const float* trend  = (const float*)d_in[0];
  const float* coarse = (const float*)d_in[1];
  const float* fine   = (const float*)d_in[2];
  const float* resid  = (const float*)d_in[3];
  const float* W_emb  = (const float*)d_in[4];
  const float* b_emb  = (const float*)d_in[5];
  const float* W1  = (const float*)d_in[6];
  const float* b1  = (const float*)d_in[7];
  const float* W2  = (const float*)d_in[8];
  const float* b2  = (const float*)d_in[9];
  const float* Wr1 = (const float*)d_in[10];
  const float* br1 = (const float*)d_in[11];
  const float* Wr2 = (const float*)d_in[12];
  const float* br2 = (const float*)d_in[13];
  float* out = (float*)d_out;

  char* p = (char*)d_ws;
  size_t off = 0;
  auto alloc = [&](size_t bytes) -> void* {
    void* r = p + off;
    off = (off + bytes + 255) & ~(size_t)255;
    return r;
  };
  unsigned short* Uh = (unsigned short*)alloc((size_t)NSEQ * 512 * 2);
  unsigned short* Ul = (unsigned short*)alloc((size_t)NSEQ * 512 * 2);
  unsigned short* Hh = (unsigned short*)alloc((size_t)NSEQ * 512 * 2);
  unsigned short* Hl = (unsigned short*)alloc((size_t)NSEQ * 512 * 2);
  float* V   = (float*)alloc((size_t)NSEQ * 256 * 4);
  float* ZL  = (float*)alloc((size_t)NSEQ * 256 * 4);
  float* ZN2 = (float*)alloc((size_t)NSEQ * 4);
  unsigned short* VO = (unsigned short*)alloc((size_t)3 * NSEQ * 256 * 2);
  float* XT  = (float*)alloc((size_t)5 * 4096 * 336 * 4);
  unsigned short* W1h = (unsigned short*)alloc((size_t)512 * 512 * 2);
  unsigned short* W1l = (unsigned short*)alloc((size_t)512 * 512 * 2);
  unsigned short* W2h = (unsigned short*)alloc((size_t)512 * 256 * 2);
  unsigned short* W2l = (unsigned short*)alloc((size_t)512 * 256 * 2);
  unsigned short* Wr1h = (unsigned short*)alloc((size_t)256 * 512 * 2);
  unsigned short* Wr1l = (unsigned short*)alloc((size_t)256 * 512 * 2);
  unsigned short* Wr2h = (unsigned short*)alloc((size_t)512 * 32 * 2);
  unsigned short* Wr2l = (unsigned short*)alloc((size_t)512 * 32 * 2);
  unsigned short* WgH = (unsigned short*)alloc((size_t)16 * 64 * 8 * 2);
  unsigned short* WgL = (unsigned short*)alloc((size_t)16 * 64 * 8 * 2);

  fold_transpose<<<dim3(64, 6), 256, 0, stream>>>(trend, coarse, fine, resid, XT);
  conv_weight<<<(512 * 512 + 255) / 256, 256, 0, stream>>>(W1, W1h, W1l, 512, 512, 512);
  conv_weight<<<(512 * 256 + 255) / 256, 256, 0, stream>>>(W2, W2h, W2l, 512, 256, 256);
  conv_weight<<<(256 * 512 + 255) / 256, 256, 0, stream>>>(Wr1, Wr1h, Wr1l, 256, 512, 512);
  conv_weight<<<(512 * 32 + 255) / 256, 256, 0, stream>>>(Wr2, Wr2h, Wr2l, 512, 32, 24);
  conv_wemb<<<32, 256, 0, stream>>>(W_emb, WgH, WgL);
  init_kernel<<<NSEQ / 4, 256, 0, stream>>>(XT, WgH, WgL, b_emb, Uh, Ul, ZL, ZN2, VO);

  for (int k = 0; k < 4; ++k) {
    // H = tanh(U @ W1 + b1)   (20480x512)@(512x512)
    gemm_split<1><<<dim3(160, 4), 256, 0, stream>>>(Uh, Ul, 512, W1h, W1l, 512, b1,
                                                    nullptr, Hh, Hl, 512);
    // V = H @ W2 + b2         (20480x512)@(512x256), f32 row-major out
    gemm_split<0><<<dim3(160, 2), 256, 0, stream>>>(Hh, Hl, 512, W2h, W2l, 256, b2,
                                                    V, nullptr, nullptr, 256);
    const unsigned short* vok = VO + (size_t)(k < 3 ? k : 0) * NSEQ * 256;
    step_kernel<<<NSEQ / 4, 256, 0, stream>>>(V, Uh, Ul, ZL, ZN2, vok, k);
    // R1 = relu(U[:,0:256] @ Wr1 + br1)  (20480x256)@(256x512)
    gemm_split<2><<<dim3(160, 4), 256, 0, stream>>>(Uh, Ul, 256, Wr1h, Wr1l, 512, br1,
                                                    nullptr, Hh, Hl, 512);
    // out slice = R1 @ Wr2 + br2
    gemm4_mfma<<<160, 256, 0, stream>>>(Hh, Hl, Wr2h, Wr2l, br2, out, k);
  }
}